// Round 2
// baseline (6188.095 us; speedup 1.0000x reference)
//
#include <hip/hip_runtime.h>
#include <stdint.h>

// Round 4: self-validating tagged h broadcast.
//  - h broadcast words are (tag<<16)|bf16(h): flag poll + data load collapse into ONE
//    LLC round trip; producer drain/vmcnt, Hloc repack, wave0 gather all deleted.
//  - Consumer loads MFMA A-frags DIRECTLY from LLC into registers (no Hs LDS staging),
//    per-wave retry on its own K-quarter (waits on only 16 producer WGs).
//  - Double-buffered Red -> exactly ONE __syncthreads per step (was 4).
//  - First wait vmcnt(5) (h loads are the 16 oldest vmem ops), retries vmcnt(0).
//  - Fast tanh/sigmoid (v_rcp + __expf) on the producer-side chain.
//  - hbuf (2 x 32 x 1024 tagged u32 = 256KB) aliases the dead xbf region; memset after gemm.

#define TT 1024
#define BB 32
#define DD 1024
#define GM (TT * BB)   // 32768
#define GN 3072
#define GK 1024
#define NBD (BB * DD)

typedef __attribute__((ext_vector_type(8))) __bf16 bf16x8;
typedef __attribute__((ext_vector_type(8))) unsigned short us8;
typedef __attribute__((ext_vector_type(4))) float f32x4;
typedef __attribute__((ext_vector_type(4))) unsigned int u32x4;
typedef unsigned short ushort_t;
typedef unsigned long long ull_t;

__device__ __forceinline__ unsigned short f2bf(float f) {
    unsigned u = __builtin_bit_cast(unsigned, f);
    return (unsigned short)((u + 0x8000u) >> 16);  // round-half-up; inputs are finite
}
__device__ __forceinline__ float bf2f(unsigned short h) {
    unsigned u = ((unsigned)h) << 16;
    return __builtin_bit_cast(float, u);
}

// ---------------------------------------------------------------- cvt fp32->bf16
__global__ __launch_bounds__(256) void cvt_f32_bf16(const float4* __restrict__ src,
                                                    ushort4* __restrict__ dst, int n4) {
    int i = blockIdx.x * 256 + threadIdx.x;
    int stride = gridDim.x * 256;
    for (; i < n4; i += stride) {
        float4 v = src[i];
        ushort4 o;
        o.x = f2bf(v.x); o.y = f2bf(v.y); o.z = f2bf(v.z); o.w = f2bf(v.w);
        dst[i] = o;
    }
}

// ---------------------------------------------------------------- GEMM: P = Xbf @ Wcat^T
// 128x128 tile, BK=64, 4 waves in 2x2, XOR-swizzled LDS (16B chunk ^ (row&7)) -> 2-way (free).
#define SUPER 16
__global__ __launch_bounds__(256) void gemm_xproj(const ushort_t* __restrict__ A,   // 32768x1024 bf16
                                                  const ushort_t* __restrict__ Bw,  // 3072x1024 bf16
                                                  ushort_t* __restrict__ P) {       // 32768x3072 bf16
    __shared__ ushort_t As[128 * 64];
    __shared__ ushort_t Bs[128 * 64];

    int bid = blockIdx.x;
    int st = bid / (SUPER * 24);
    int r  = bid % (SUPER * 24);
    int tm = st * SUPER + (r & (SUPER - 1));   // supertile order: 16 M-tiles share A in L2/LLC
    int tn = r / SUPER;

    int tid = threadIdx.x;
    int lane = tid & 63, wv = tid >> 6;
    int wm = wv >> 1, wn = wv & 1;
    int l15 = lane & 15, q = lane >> 4;

    f32x4 acc[4][4];
#pragma unroll
    for (int mi = 0; mi < 4; mi++)
#pragma unroll
        for (int ni = 0; ni < 4; ni++) acc[mi][ni] = (f32x4){0.f, 0.f, 0.f, 0.f};

    const ushort_t* Abase = A + (size_t)(tm * 128) * GK;
    const ushort_t* Bbase = Bw + (size_t)(tn * 128) * GK;
    int c8 = tid & 7, rr = tid >> 3;  // rr: 0..31

    for (int kit = 0; kit < 16; kit++) {
        int k0 = kit * 64;
        if (kit) __syncthreads();
#pragma unroll
        for (int p = 0; p < 4; p++) {
            int row = p * 32 + rr;
            int sw = c8 ^ (row & 7);
            uint4 va = *(const uint4*)(Abase + (size_t)row * GK + k0 + c8 * 8);
            *(uint4*)&As[row * 64 + sw * 8] = va;
            uint4 vb = *(const uint4*)(Bbase + (size_t)row * GK + k0 + c8 * 8);
            *(uint4*)&Bs[row * 64 + sw * 8] = vb;
        }
        __syncthreads();
#pragma unroll
        for (int ks = 0; ks < 2; ks++) {
            bf16x8 af[4], bfr[4];
#pragma unroll
            for (int mi = 0; mi < 4; mi++) {
                int rl = wm * 64 + mi * 16 + l15;
                int sw = (ks * 4 + q) ^ (rl & 7);
                af[mi] = *(const bf16x8*)&As[rl * 64 + sw * 8];
            }
#pragma unroll
            for (int ni = 0; ni < 4; ni++) {
                int rl = wn * 64 + ni * 16 + l15;
                int sw = (ks * 4 + q) ^ (rl & 7);
                bfr[ni] = *(const bf16x8*)&Bs[rl * 64 + sw * 8];
            }
#pragma unroll
            for (int mi = 0; mi < 4; mi++)
#pragma unroll
                for (int ni = 0; ni < 4; ni++)
                    acc[mi][ni] = __builtin_amdgcn_mfma_f32_16x16x32_bf16(af[mi], bfr[ni], acc[mi][ni], 0, 0, 0);
        }
    }
    // epilogue: C/D layout col=lane&15, row=(lane>>4)*4+reg  [verified m89/m91]
#pragma unroll
    for (int mi = 0; mi < 4; mi++)
#pragma unroll
        for (int ni = 0; ni < 4; ni++) {
            int n = tn * 128 + wn * 64 + ni * 16 + l15;
#pragma unroll
            for (int i = 0; i < 4; i++) {
                int m = tm * 128 + wm * 64 + mi * 16 + q * 4 + i;
                P[(size_t)m * GN + n] = f2bf(acc[mi][ni][i]);
            }
        }
}

// ---------------------------------------------------------------- persistent RNN scan
// 128 WGs: bg = blockIdx>>6 (2 chains of 16 batches), slice = blockIdx&63 (16 dims each).
// h broadcast: tagged u32 words ((t<<16)|bf16), double-buffered. Consumers load their
// A-fragments straight from LLC (sc0 sc1) and spin until all tags match t. Producers
// store one tagged word per thread, fire-and-forget. One __syncthreads per step.
__global__ __launch_bounds__(256, 1) void rnn_scan(
    const float* __restrict__ Ua, const float* __restrict__ Ub, const float* __restrict__ Wh,
    const float* __restrict__ ba, const float* __restrict__ bb, const float* __restrict__ bv,
    const ushort_t* __restrict__ P,     // 32768x3072 bf16
    unsigned int* __restrict__ hbuf,    // 2 x 32 x 1024 tagged u32 (double-buffered)
    float* __restrict__ out) {

    __shared__ float Red[2][4][3][16][16];            // 24KB double-buffered K-split partials

    int g = blockIdx.x;
    int slice = g & 63, bg = g >> 6;
    int e0 = slice * 16;
    int tid = threadIdx.x, lane = tid & 63, wv = tid >> 6;
    int l15 = lane & 15, q = lane >> 4;

    // ---- preload recurrent weight fragments into registers (96 VGPR/lane)
    bf16x8 wf[3][8];
#pragma unroll
    for (int nt = 0; nt < 3; nt++) {
        const float* Um = (nt == 0) ? Ua : (nt == 1) ? Ub : Wh;
#pragma unroll
        for (int ks = 0; ks < 8; ks++) {
            int e = e0 + l15;
            int d = wv * 256 + ks * 32 + q * 8;
            const float* p = Um + (size_t)e * DD + d;
            us8 u;
#pragma unroll
            for (int j = 0; j < 8; j++) u[j] = f2bf(p[j]);
            wf[nt][ks] = __builtin_bit_cast(bf16x8, u);
        }
    }

    // ---- per-thread ownership for the elementwise epilogue: thread = (batch, dim)
    int bcomb = tid >> 4;            // 0..15 batch-local
    int ncomb = tid & 15;            // 0..15 dim-local
    int bglob = bg * 16 + bcomb;
    int ecomb = e0 + ncomb;
    float bias_a = ba[ecomb], bias_b = bb[ecomb], bias_v = bv[ecomb];
    float hreg = 0.f;                // fp32 master h state lives here across all steps
    int hoff = bglob * DD + ecomb;

    // per-lane h-load base: row l15 of this chain, k-offset wv*256 + q*8 (word units)
    const unsigned int* hb0 = hbuf + (size_t)bg * 16 * DD + (size_t)l15 * DD + wv * 256 + q * 8;
    // producer tagged-word address (this thread's (batch,dim))
    unsigned int* hst = hbuf + (size_t)(bg * 16 + bcomb) * DD + e0 + ncomb;

    float hn_keep = 0.f, o1_keep = 0.f;

#define HLD(i, off) asm volatile("global_load_dwordx4 %0, %1, off offset:" off " sc0 sc1" \
                                 : "=v"(hv[i]) : "v"(hp) : "memory")
#define HLOADS() do { \
        HLD(0, "0");   HLD(1, "16");  HLD(2, "128"); HLD(3, "144");  \
        HLD(4, "256"); HLD(5, "272"); HLD(6, "384"); HLD(7, "400");  \
        HLD(8, "512"); HLD(9, "528"); HLD(10, "640"); HLD(11, "656"); \
        HLD(12, "768"); HLD(13, "784"); HLD(14, "896"); HLD(15, "912"); } while (0)

    for (int t = 0; t < TT; t++) {
        // (1) issue tagged h loads FIRST (they are the 16 oldest vmem ops -> vmcnt(5))
        const unsigned int* hp = hb0 + ((t & 1) ? NBD : 0);
        u32x4 hv[16];
        HLOADS();

        // (2) deferred out stores from step t-1 (t=0: both write the h[0]=0 slot)
        size_t o_hn = (size_t)(TT + t) * NBD + hoff;
        size_t o_o1 = t ? ((size_t)(t - 1) * NBD + hoff) : o_hn;
        out[o_hn] = hn_keep;
        out[o_o1] = o1_keep;

        // (3) x-projection loads (HBM; drain later, overlapped with the wait below)
        const ushort_t* pp = P + ((size_t)t * BB + bglob) * GN + ecomb;
        unsigned short pax = pp[0];
        unsigned short pbx = pp[DD];
        unsigned short pwx = pp[2 * DD];

        // (4) wait for this wave's K-quarter: all 64 tags must equal t
        unsigned texp = (unsigned)t << 16;
        asm volatile("s_waitcnt vmcnt(5)" ::: "memory");   // h loads are the 16 oldest
        __builtin_amdgcn_sched_barrier(0);
        for (;;) {
            unsigned bad = 0;
#pragma unroll
            for (int i = 0; i < 16; i++)
#pragma unroll
                for (int j = 0; j < 4; j++)
                    bad |= (hv[i][j] ^ texp) & 0xffff0000u;
            if (__all((int)(bad == 0))) break;
            __builtin_amdgcn_s_sleep(2);
            HLOADS();
            asm volatile("s_waitcnt vmcnt(0)" ::: "memory");
            __builtin_amdgcn_sched_barrier(0);
        }

        // (5) pack bf16 A-frags from tagged words and run the 24 MFMAs
        f32x4 a0 = {0.f,0.f,0.f,0.f}, a1 = {0.f,0.f,0.f,0.f}, a2 = {0.f,0.f,0.f,0.f};
#pragma unroll
        for (int ks = 0; ks < 8; ks++) {
            u32x4 w0 = hv[2 * ks], w1 = hv[2 * ks + 1];
            unsigned p0 = (w0[1] << 16) | (w0[0] & 0xffffu);
            unsigned p1 = (w0[3] << 16) | (w0[2] & 0xffffu);
            unsigned p2 = (w1[1] << 16) | (w1[0] & 0xffffu);
            unsigned p3 = (w1[3] << 16) | (w1[2] & 0xffffu);
            u32x4 pk = (u32x4){p0, p1, p2, p3};
            bf16x8 af = __builtin_bit_cast(bf16x8, pk);
            a0 = __builtin_amdgcn_mfma_f32_16x16x32_bf16(af, wf[0][ks], a0, 0, 0, 0);
            a1 = __builtin_amdgcn_mfma_f32_16x16x32_bf16(af, wf[1][ks], a1, 0, 0, 0);
            a2 = __builtin_amdgcn_mfma_f32_16x16x32_bf16(af, wf[2][ks], a2, 0, 0, 0);
        }
        int rb = t & 1;
#pragma unroll
        for (int i = 0; i < 4; i++) {
            Red[rb][wv][0][q * 4 + i][l15] = a0[i];
            Red[rb][wv][1][q * 4 + i][l15] = a1[i];
            Red[rb][wv][2][q * 4 + i][l15] = a2[i];
        }
        __syncthreads();                                  // the ONLY barrier per step

        // (6) combine: K-reduce across waves, gates, h update
        float pa = 0.f, pb = 0.f, pv = 0.f;
#pragma unroll
        for (int w = 0; w < 4; w++) {
            pa += Red[rb][w][0][bcomb][ncomb];
            pb += Red[rb][w][1][bcomb][ncomb];
            pv += Red[rb][w][2][bcomb][ncomb];
        }
        float aval = pa + bf2f(pax) + bias_a;
        float bval = pb + bf2f(pbx) + bias_b;
        float vval = pv + bf2f(pwx) + bias_v;
        float alpha = __builtin_amdgcn_rcpf(1.f + __expf(-aval));
        float beta  = __builtin_amdgcn_rcpf(1.f + __expf(-bval));
        float vc    = fminf(fmaxf(vval, -15.f), 15.f);
        float e2    = __expf(2.f * vc);
        float vtan  = (e2 - 1.f) * __builtin_amdgcn_rcpf(e2 + 1.f);
        float hn = alpha * hreg + beta * vtan;
        hreg = hn;
        float sg = __builtin_amdgcn_rcpf(1.f + __expf(-hn));
        hn_keep = hn;
        o1_keep = hn * hn * sg;

        // (7) fire-and-forget tagged h word (tag t+1); ack drains in next step's wait
        if (t < TT - 1) {
            unsigned wordv = ((unsigned)(t + 1) << 16) | (unsigned)f2bf(hn);
            unsigned int* hd = hst + (((t + 1) & 1) ? NBD : 0);
            asm volatile("global_store_dword %0, %1, off sc0 sc1"
                         :: "v"(hd), "v"(wordv) : "memory");
        }
    }
    // final step's outputs
    out[(size_t)(2 * TT) * NBD + hoff] = hn_keep;               // h[TT]
    out[(size_t)(TT - 1) * NBD + hoff] = o1_keep;               // out[TT-1]
#undef HLD
#undef HLOADS
}

// ---------------------------------------------------------------- launch
extern "C" void kernel_launch(void* const* d_in, const int* in_sizes, int n_in,
                              void* d_out, int out_size, void* d_ws, size_t ws_size,
                              hipStream_t stream) {
    const float* x   = (const float*)d_in[0];
    const float* Wa  = (const float*)d_in[1];
    const float* Uaw = (const float*)d_in[2];
    const float* bal = (const float*)d_in[3];
    const float* Wb  = (const float*)d_in[4];
    const float* Ubw = (const float*)d_in[5];
    const float* bbe = (const float*)d_in[6];
    const float* Whw = (const float*)d_in[7];
    const float* Wx  = (const float*)d_in[8];
    const float* bw  = (const float*)d_in[9];
    float* out = (float*)d_out;

    // ws layout (262.1 MiB, unchanged footprint):
    //   P    [0, 201326592)            32768x3072 bf16
    //   xbf  [201326592, 268435456)    32768x1024 bf16  -- DEAD after gemm
    //   Wcat [268435456, 274726912)    3x1024x1024 bf16
    //   hbuf aliases xbf start: 2 x 32 x 1024 tagged u32 = 262144 B (memset AFTER gemm)
    char* ws = (char*)d_ws;
    ushort_t* P    = (ushort_t*)ws;
    ushort_t* xbf  = (ushort_t*)(ws + 201326592);
    ushort_t* Wcat = (ushort_t*)(ws + 268435456);
    unsigned int* hbuf = (unsigned int*)(ws + 201326592);   // alias: xbf is dead post-gemm

    cvt_f32_bf16<<<512, 256, 0, stream>>>((const float4*)x,  (ushort4*)xbf,  (GM * GK) / 4);
    cvt_f32_bf16<<<64, 256, 0, stream>>>((const float4*)Wa, (ushort4*)Wcat, (DD * DD) / 4);
    cvt_f32_bf16<<<64, 256, 0, stream>>>((const float4*)Wb, (ushort4*)(Wcat + DD * DD), (DD * DD) / 4);
    cvt_f32_bf16<<<64, 256, 0, stream>>>((const float4*)Wx, (ushort4*)(Wcat + 2 * DD * DD), (DD * DD) / 4);

    gemm_xproj<<<(GM / 128) * (GN / 128), 256, 0, stream>>>(xbf, Wcat, P);

    // zero tagged h0 (tag 0 == step 0, value 0) -- stream-ordered after gemm read of xbf
    hipMemsetAsync(hbuf, 0, 2 * NBD * sizeof(unsigned int), stream);

    rnn_scan<<<128, 256, 0, stream>>>(Uaw, Ubw, Whw, bal, bbe, bw, P, hbuf, out);
}